// Round 5
// baseline (193.500 us; speedup 1.0000x reference)
//
#include <hip/hip_runtime.h>

#define D_MODEL 768
#define N_HEADS 12
#define DK      64
#define BB      2
#define SS      2048
#define PH      (BB*SS*D_MODEL)      // 3,145,728 elems
#define WN      (D_MODEL*D_MODEL)    // 589,824 elems

typedef short bf8_t   __attribute__((ext_vector_type(8)));   // 8 x bf16 bits
typedef float f32x4   __attribute__((ext_vector_type(4)));

// f32 -> bf16 bits, round-to-nearest-even (finite inputs)
__device__ __forceinline__ unsigned short f2b(float f) {
  unsigned u = __builtin_bit_cast(unsigned, f);
  unsigned r = (u + 0x7FFFu + ((u >> 16) & 1u)) >> 16;
  return (unsigned short)r;
}
__device__ __forceinline__ unsigned pk2(float a, float b) {
  return (unsigned)f2b(a) | ((unsigned)f2b(b) << 16);
}
__device__ __forceinline__ f32x4 mfma16(bf8_t a, bf8_t b, f32x4 c) {
  return __builtin_amdgcn_mfma_f32_16x16x32_bf16(a, b, c, 0, 0, 0);
}

// Load one 16x32 fragment from a swizzled 64-wide bf16 LDS tile.
// lane: row = rbase + (lane&15), k = kk*32 + (lane>>4)*8 + j (j=0..7)
__device__ __forceinline__ bf8_t ld_frag64(const unsigned short* t, int rbase, int kk, int lane) {
  int row = rbase + (lane & 15);
  int k = (kk << 5) + ((lane >> 4) << 3);
  uint4 u = *(const uint4*)&t[(row << 6) + (k ^ ((row & 7) << 3))];
  return __builtin_bit_cast(bf8_t, u);
}

// Write one 16B chunk (row rr, k-chunk k8) into swizzled 64-wide LDS tile.
__device__ __forceinline__ void st_row(unsigned short* lds, int rr, int k8, uint4 a) {
  *(uint4*)&lds[(rr << 6) + ((k8 ^ (rr & 7)) << 3)] = a;
}

// ---------------------------------------------------------------------------
// prep: convert q,k,v (3 x PH f32) and wq,wk,wv,wo (4 x WN f32) to bf16.
// ---------------------------------------------------------------------------
__global__ __launch_bounds__(256)
void prep(const float* __restrict__ q, const float* __restrict__ k, const float* __restrict__ v,
          const float* __restrict__ wq, const float* __restrict__ wk,
          const float* __restrict__ wv, const float* __restrict__ wo,
          unsigned short* __restrict__ dst) {
  const int QKV_C = PH / 8;
  const int W_C   = WN / 8;
  const int TOTAL = 3 * QKV_C + 4 * W_C;
  for (int c = blockIdx.x * 256 + threadIdx.x; c < TOTAL; c += gridDim.x * 256) {
    const float* s;
    int off;
    if (c < 3 * QKV_C) {
      int seg = c / QKV_C; off = c - seg * QKV_C;
      s = seg == 0 ? q : seg == 1 ? k : v;
    } else {
      int c2 = c - 3 * QKV_C;
      int seg = c2 / W_C; off = c2 - seg * W_C;
      s = seg == 0 ? wq : seg == 1 ? wk : seg == 2 ? wv : wo;
    }
    const float* p = s + (size_t)off * 8;
    float4 a = *(const float4*)p;
    float4 b = *(const float4*)(p + 4);
    uint4 o;
    o.x = pk2(a.x, a.y); o.y = pk2(a.z, a.w);
    o.z = pk2(b.x, b.y); o.w = pk2(b.z, b.w);
    *(uint4*)&dst[(size_t)c * 8] = o;
  }
}

// ---------------------------------------------------------------------------
// Fused QKV projection, 128x64 tile, 4 waves (each 32 rows x 64 cols).
// Grid 1152 1D XCD-chunked. z=0: Q*0.125 -> [B,H,S,dk]; z=1: K -> [B,H,S,dk];
// z=2: V -> [B,H,dk,S] (transposed).
// ---------------------------------------------------------------------------
__global__ __launch_bounds__(256)
void qkv_proj(const unsigned short* __restrict__ Qc, const unsigned short* __restrict__ Kc,
              const unsigned short* __restrict__ Vc,
              const unsigned short* __restrict__ Wq, const unsigned short* __restrict__ Wk,
              const unsigned short* __restrict__ Wv,
              const float* __restrict__ bq, const float* __restrict__ bk,
              const float* __restrict__ bv,
              unsigned short* __restrict__ Qh, unsigned short* __restrict__ Kh,
              unsigned short* __restrict__ VT) {
  __shared__ __align__(16) unsigned short As[128 * 64];   // 16 KB
  __shared__ __align__(16) unsigned short Ws[64 * 64];    // 8 KB
  const int tid = threadIdx.x, lane = tid & 63, w = tid >> 6;
  const int g = lane >> 4, qc = lane & 15;
  const int p = blockIdx.x;
  const int l = (p & 7) * 144 + (p >> 3);
  const int z = l / 384, rr = l % 384;
  const int m0 = (rr / 12) << 7, n0 = (rr % 12) << 6;

  const unsigned short* A = z == 0 ? Qc : z == 1 ? Kc : Vc;
  const unsigned short* W = z == 0 ? Wq : z == 1 ? Wk : Wv;
  const float* bias = z == 0 ? bq : z == 1 ? bk : bv;
  const float oscale = z == 0 ? 0.125f : 1.0f;

  const int r0 = tid >> 3, k8 = tid & 7;
  const unsigned short* Ab = A + (size_t)(m0 + r0) * D_MODEL + (k8 << 3);
  const unsigned short* Wb = W + (size_t)(n0 + r0) * D_MODEL + (k8 << 3);

  uint4 ra[4], rw[2];
#pragma unroll
  for (int i = 0; i < 4; ++i) ra[i] = *(const uint4*)(Ab + (size_t)(i * 32) * D_MODEL);
#pragma unroll
  for (int i = 0; i < 2; ++i) rw[i] = *(const uint4*)(Wb + (size_t)(i * 32) * D_MODEL);

  f32x4 acc[2][4] = {};
  for (int kt = 0; kt < 12; ++kt) {
    __syncthreads();
#pragma unroll
    for (int i = 0; i < 4; ++i) st_row(As, r0 + i * 32, k8, ra[i]);
#pragma unroll
    for (int i = 0; i < 2; ++i) st_row(Ws, r0 + i * 32, k8, rw[i]);
    __syncthreads();
    if (kt < 11) {
      int off = (kt + 1) << 6;
#pragma unroll
      for (int i = 0; i < 4; ++i) ra[i] = *(const uint4*)(Ab + (size_t)(i * 32) * D_MODEL + off);
#pragma unroll
      for (int i = 0; i < 2; ++i) rw[i] = *(const uint4*)(Wb + (size_t)(i * 32) * D_MODEL + off);
    }
#pragma unroll
    for (int kk = 0; kk < 2; ++kk) {
      bf8_t a0 = ld_frag64(As, (w << 5), kk, lane);
      bf8_t a1 = ld_frag64(As, (w << 5) + 16, kk, lane);
#pragma unroll
      for (int n = 0; n < 4; ++n) {
        bf8_t bn = ld_frag64(Ws, n << 4, kk, lane);
        acc[0][n] = mfma16(a0, bn, acc[0][n]);
        acc[1][n] = mfma16(a1, bn, acc[1][n]);
      }
    }
  }

  const int b = m0 >> 11;
  const int h = n0 >> 6;
  if (z < 2) {
    unsigned short* dst = (z == 0 ? Qh : Kh) + ((size_t)(b * N_HEADS + h)) * SS * DK;
#pragma unroll
    for (int i = 0; i < 2; ++i) {
#pragma unroll
      for (int n = 0; n < 4; ++n) {
        int col = (n << 4) + qc;
        float bb = bias[n0 + col];
#pragma unroll
        for (int r = 0; r < 4; ++r) {
          int s = (m0 + (w << 5) + (i << 4) + (g << 2) + r) & (SS - 1);
          dst[(size_t)s * DK + col] = f2b((acc[i][n][r] + bb) * oscale);
        }
      }
    }
  } else {
    unsigned short* dst = VT + ((size_t)(b * N_HEADS + h)) * DK * SS;
#pragma unroll
    for (int i = 0; i < 2; ++i) {
#pragma unroll
      for (int n = 0; n < 4; ++n) {
        int col = (n << 4) + qc;          // d index
        float bb = bias[n0 + col];
        int s = (m0 + (w << 5) + (i << 4) + (g << 2)) & (SS - 1);
        ushort4 pk;
        pk.x = f2b(acc[i][n][0] + bb); pk.y = f2b(acc[i][n][1] + bb);
        pk.z = f2b(acc[i][n][2] + bb); pk.w = f2b(acc[i][n][3] + bb);
        *(ushort4*)&dst[(size_t)col * SS + s] = pk;
      }
    }
  }
}

// ---------------------------------------------------------------------------
// MFMA causal attention, swapped-operand scores (S^T = K x Q^T), dbuf LDS.
// Grid 768 1D XCD-chunked: 24 bh x 32 paired q-tiles of 64 rows, 4 waves.
// ---------------------------------------------------------------------------
__global__ __launch_bounds__(256)
void attn3(const unsigned short* __restrict__ Qh, const unsigned short* __restrict__ Kh,
           const unsigned short* __restrict__ VT,
           float* __restrict__ attn, unsigned short* __restrict__ ctx) {
  __shared__ __align__(16) unsigned short Ks[2][4096];    // 16 KB
  __shared__ __align__(16) unsigned short Vts[2][4096];   // 16 KB
  __shared__ __align__(16) unsigned short Pw[4][1024];    // 8 KB

  const int tid = threadIdx.x, lane = tid & 63, w = tid >> 6;
  const int g = lane >> 4, qc = lane & 15;
  const int p = blockIdx.x;
  const int l = (p & 7) * 96 + (p >> 3);
  const int bh = l >> 5;
  const int x = l & 31;
  const int qt = (x & 1) ? (31 - (x >> 1)) : (x >> 1);
  const int q0 = qt << 6;
  const int b = bh / N_HEADS, h = bh - b * N_HEADS;

  const unsigned short* Qb = Qh + (size_t)bh * SS * DK;
  const unsigned short* Kb = Kh + (size_t)bh * SS * DK;
  const unsigned short* Vb = VT + (size_t)bh * DK * SS;
  float* attn_b = attn + (size_t)bh * SS * SS;

  // Q fragments straight from global (used as the MFMA B-operand)
  bf8_t qf0, qf1;
  {
    const unsigned short* qp = &Qb[(size_t)(q0 + (w << 4) + qc) * DK + (g << 3)];
    qf0 = __builtin_bit_cast(bf8_t, *(const uint4*)qp);
    qf1 = __builtin_bit_cast(bf8_t, *(const uint4*)(qp + 32));
  }

  const int r0 = tid >> 3, k8 = tid & 7;
  auto ldK = [&](int t, uint4& a0, uint4& a1) {
    const unsigned short* bse = Kb + ((size_t)t << 12);
    a0 = *(const uint4*)&bse[(r0 << 6) + (k8 << 3)];
    a1 = *(const uint4*)&bse[((r0 + 32) << 6) + (k8 << 3)];
  };
  auto ldV = [&](int t, uint4& a0, uint4& a1) {
    const unsigned short* bse = Vb + (t << 6);
    a0 = *(const uint4*)&bse[(size_t)r0 * SS + (k8 << 3)];
    a1 = *(const uint4*)&bse[(size_t)(r0 + 32) * SS + (k8 << 3)];
  };

  const int qglob = q0 + (w << 4) + qc;   // this lane's q row (scores are S^T)
  float l_acc = 0.f;

  // ---------------- pass 1: row sums ----------------
  {
    uint4 ka0, ka1;
    ldK(0, ka0, ka1);
    for (int t = 0; t <= qt; ++t) {
      unsigned short* KB = Ks[t & 1];
      st_row(KB, r0, k8, ka0);
      st_row(KB, r0 + 32, k8, ka1);
      __syncthreads();
      if (t < qt) ldK(t + 1, ka0, ka1);
      f32x4 sc[4] = {};
      __builtin_amdgcn_s_setprio(1);
#pragma unroll
      for (int kk = 0; kk < 2; ++kk) {
        bf8_t qf = kk ? qf1 : qf0;
#pragma unroll
        for (int n = 0; n < 4; ++n)
          sc[n] = mfma16(ld_frag64(KB, n << 4, kk, lane), qf, sc[n]);
      }
      __builtin_amdgcn_s_setprio(0);
      const bool diag = (t == qt);
      const int k0 = t << 6;
      float part = 0.f;
#pragma unroll
      for (int n = 0; n < 4; ++n) {
        int kb = k0 + (n << 4) + (g << 2);
#pragma unroll
        for (int r = 0; r < 4; ++r) {
          bool ok = !diag || (kb + r <= qglob);
          part += ok ? __expf(sc[n][r]) : 0.f;
        }
      }
      part += __shfl_xor(part, 16);
      part += __shfl_xor(part, 32);
      l_acc += part;
      __syncthreads();
    }
  }

  const float Linv = 1.0f / l_acc;

  // ---------------- pass 2: attn write + PV ----------------
  f32x4 ct[4] = {};
  unsigned short* myP = Pw[w];
  {
    uint4 ka0, ka1, va0, va1;
    ldK(0, ka0, ka1);
    ldV(0, va0, va1);
    __syncthreads();
    for (int t = 0; t <= qt; ++t) {
      unsigned short* KB = Ks[t & 1];
      unsigned short* VB = Vts[t & 1];
      st_row(KB, r0, k8, ka0);
      st_row(KB, r0 + 32, k8, ka1);
      st_row(VB, r0, k8, va0);
      st_row(VB, r0 + 32, k8, va1);
      __syncthreads();
      if (t < qt) { ldK(t + 1, ka0, ka1); ldV(t + 1, va0, va1); }
      f32x4 sc[4] = {};
      __builtin_amdgcn_s_setprio(1);
#pragma unroll
      for (int kk = 0; kk < 2; ++kk) {
        bf8_t qf = kk ? qf1 : qf0;
#pragma unroll
        for (int n = 0; n < 4; ++n)
          sc[n] = mfma16(ld_frag64(KB, n << 4, kk, lane), qf, sc[n]);
      }
      __builtin_amdgcn_s_setprio(0);
      const bool diag = (t == qt);
      const int k0 = t << 6;
#pragma unroll
      for (int n = 0; n < 4; ++n) {
        int klocal = (n << 4) + (g << 2);
        int kb = k0 + klocal;
        f32x4 pv;
        float pr[4];
#pragma unroll
        for (int r = 0; r < 4; ++r) {
          bool ok = !diag || (kb + r <= qglob);
          pr[r] = ok ? __expf(sc[n][r]) * Linv : 0.f;
        }
        pv[0] = pr[0]; pv[1] = pr[1]; pv[2] = pr[2]; pv[3] = pr[3];
        __builtin_nontemporal_store(pv, (f32x4*)&attn_b[(size_t)qglob * SS + kb]);
        // P^T -> wave-private LDS tile [q=16][k=64], swizzled, as bf16 pairs
        uint2 pk;
        pk.x = pk2(pr[0], pr[1]);
        pk.y = pk2(pr[2], pr[3]);
        *(uint2*)&myP[(qc << 6) + (klocal ^ ((qc & 7) << 3))] = pk;
      }
      asm volatile("s_waitcnt lgkmcnt(0)" ::: "memory");
      __builtin_amdgcn_sched_barrier(0);
      __builtin_amdgcn_s_setprio(1);
#pragma unroll
      for (int kk = 0; kk < 2; ++kk) {
        bf8_t pf = ld_frag64(myP, 0, kk, lane);
#pragma unroll
        for (int n = 0; n < 4; ++n)
          ct[n] = mfma16(pf, ld_frag64(VB, n << 4, kk, lane), ct[n]);
      }
      __builtin_amdgcn_s_setprio(0);
      __syncthreads();
    }
  }

  // zero-fill masked upper-triangular tiles (coalesced f32x4, nontemporal)
  {
    const int zr = tid >> 4;
    const int zc = (tid & 15) << 2;
    const f32x4 z4 = {0.f, 0.f, 0.f, 0.f};
    for (int c0 = q0 + 64; c0 < SS; c0 += 64) {
#pragma unroll
      for (int i = 0; i < 4; ++i)
        __builtin_nontemporal_store(z4, (f32x4*)&attn_b[(size_t)(q0 + zr + (i << 4)) * SS + c0 + zc]);
    }
  }

  // ctx (bf16) as [B, S, H*dk];  PV C-layout: row=q=(g<<2)+r, col=d=(n<<4)+qc
  const int wrow = (w << 4) + (g << 2);
#pragma unroll
  for (int n = 0; n < 4; ++n) {
#pragma unroll
    for (int r = 0; r < 4; ++r) {
      int m = q0 + wrow + r;
      int col = (n << 4) + qc;
      ctx[((size_t)(b * SS + m)) * D_MODEL + h * DK + col] = f2b(ct[n][r]);
    }
  }
}

// ---------------------------------------------------------------------------
// Output projection: bf16 A [4096][768] @ bf16 Wo^T + bo -> f32.  128x64 tile.
// ---------------------------------------------------------------------------
__global__ __launch_bounds__(256)
void out_proj(const unsigned short* __restrict__ A, const unsigned short* __restrict__ W,
              const float* __restrict__ bias, float* __restrict__ out) {
  __shared__ __align__(16) unsigned short As[128 * 64];
  __shared__ __align__(16) unsigned short Ws[64 * 64];
  const int tid = threadIdx.x, lane = tid & 63, w = tid >> 6;
  const int g = lane >> 4, qc = lane & 15;
  const int p = blockIdx.x;
  const int l = (p & 7) * 48 + (p >> 3);
  const int m0 = (l / 12) << 7, n0 = (l % 12) << 6;

  const int r0 = tid >> 3, k8 = tid & 7;
  const unsigned short* Ab = A + (size_t)(m0 + r0) * D_MODEL + (k8 << 3);
  const unsigned short* Wb = W + (size_t)(n0 + r0) * D_MODEL + (k8 << 3);

  uint4 ra[4], rw[2];
#pragma unroll
  for (int i = 0; i < 4; ++i) ra[i] = *(const uint4*)(Ab + (size_t)(i * 32) * D_MODEL);
#pragma unroll
  for (int i = 0; i < 2; ++i) rw[i] = *(const uint4*)(Wb + (size_t)(i * 32) * D_MODEL);

  f32x4 acc[2][4] = {};
  for (int kt = 0; kt < 12; ++kt) {
    __syncthreads();
#pragma unroll
    for (int i = 0; i < 4; ++i) st_row(As, r0 + i * 32, k8, ra[i]);
#pragma unroll
    for (int i = 0; i < 2; ++i) st_row(Ws, r0 + i * 32, k8, rw[i]);
    __syncthreads();
    if (kt < 11) {
      int off = (kt + 1) << 6;
#pragma unroll
      for (int i = 0; i < 4; ++i) ra[i] = *(const uint4*)(Ab + (size_t)(i * 32) * D_MODEL + off);
#pragma unroll
      for (int i = 0; i < 2; ++i) rw[i] = *(const uint4*)(Wb + (size_t)(i * 32) * D_MODEL + off);
    }
#pragma unroll
    for (int kk = 0; kk < 2; ++kk) {
      bf8_t a0 = ld_frag64(As, (w << 5), kk, lane);
      bf8_t a1 = ld_frag64(As, (w << 5) + 16, kk, lane);
#pragma unroll
      for (int n = 0; n < 4; ++n) {
        bf8_t bn = ld_frag64(Ws, n << 4, kk, lane);
        acc[0][n] = mfma16(a0, bn, acc[0][n]);
        acc[1][n] = mfma16(a1, bn, acc[1][n]);
      }
    }
  }

#pragma unroll
  for (int i = 0; i < 2; ++i) {
#pragma unroll
    for (int n = 0; n < 4; ++n) {
      int col = n0 + (n << 4) + qc;
      float bb = bias[col];
#pragma unroll
      for (int r = 0; r < 4; ++r) {
        int m = m0 + (w << 5) + (i << 4) + (g << 2) + r;
        out[(size_t)m * D_MODEL + col] = acc[i][n][r] + bb;
      }
    }
  }
}

// ---------------------------------------------------------------------------
extern "C" void kernel_launch(void* const* d_in, const int* in_sizes, int n_in,
                              void* d_out, int out_size, void* d_ws, size_t ws_size,
                              hipStream_t stream) {
  const float* q  = (const float*)d_in[0];
  const float* k  = (const float*)d_in[1];
  const float* v  = (const float*)d_in[2];
  // d_in[3] = mask (int32 tril; causal structure exploited directly)
  const float* wq = (const float*)d_in[4];
  const float* bq = (const float*)d_in[5];
  const float* wk = (const float*)d_in[6];
  const float* bk = (const float*)d_in[7];
  const float* wv = (const float*)d_in[8];
  const float* bv = (const float*)d_in[9];
  const float* wo = (const float*)d_in[10];
  const float* bo = (const float*)d_in[11];

  float* out  = (float*)d_out;                    // [B*S, 768]
  float* attn = out + (size_t)BB * SS * D_MODEL;  // [B*H, S, S]

  unsigned short* wsu = (unsigned short*)d_ws;
  unsigned short* Qc  = wsu;
  unsigned short* Kc  = Qc + PH;
  unsigned short* Vc  = Kc + PH;
  unsigned short* Wqb = Vc + PH;
  unsigned short* Wkb = Wqb + WN;
  unsigned short* Wvb = Wkb + WN;
  unsigned short* Wob = Wvb + WN;
  unsigned short* Qhd = Wob + WN;                 // [B,H,S,dk]
  unsigned short* Khd = Qhd + PH;
  unsigned short* VTw = Khd + PH;                 // [B,H,dk,S]
  unsigned short* Cw  = VTw + PH;                 // [B,S,768]

  dim3 blk(256);
  prep<<<2048, blk, 0, stream>>>(q, k, v, wq, wk, wv, wo, wsu);
  qkv_proj<<<1152, blk, 0, stream>>>(Qc, Kc, Vc, Wqb, Wkb, Wvb, bq, bk, bv, Qhd, Khd, VTw);
  attn3<<<768, blk, 0, stream>>>(Qhd, Khd, VTw, attn, Cw);
  out_proj<<<384, blk, 0, stream>>>(Cw, Wob, bo, out);
}

// Round 6
// 183.391 us; speedup vs baseline: 1.0551x; 1.0551x over previous
//
#include <hip/hip_runtime.h>

#define D_MODEL 768
#define N_HEADS 12
#define DK      64
#define BB      2
#define SS      2048
#define PH      (BB*SS*D_MODEL)      // 3,145,728 elems
#define WN      (D_MODEL*D_MODEL)    // 589,824 elems

typedef short bf8_t   __attribute__((ext_vector_type(8)));   // 8 x bf16 bits
typedef float f32x4   __attribute__((ext_vector_type(4)));

// f32 -> bf16 bits, round-to-nearest-even (finite inputs)
__device__ __forceinline__ unsigned short f2b(float f) {
  unsigned u = __builtin_bit_cast(unsigned, f);
  unsigned r = (u + 0x7FFFu + ((u >> 16) & 1u)) >> 16;
  return (unsigned short)r;
}
__device__ __forceinline__ unsigned pk2(float a, float b) {
  return (unsigned)f2b(a) | ((unsigned)f2b(b) << 16);
}
__device__ __forceinline__ f32x4 mfma16(bf8_t a, bf8_t b, f32x4 c) {
  return __builtin_amdgcn_mfma_f32_16x16x32_bf16(a, b, c, 0, 0, 0);
}

// Load one 16x32 fragment from a swizzled 64-wide bf16 LDS tile.
// lane: row = rbase + (lane&15), k = kk*32 + (lane>>4)*8 + j (j=0..7)
__device__ __forceinline__ bf8_t ld_frag64(const unsigned short* t, int rbase, int kk, int lane) {
  int row = rbase + (lane & 15);
  int k = (kk << 5) + ((lane >> 4) << 3);
  uint4 u = *(const uint4*)&t[(row << 6) + (k ^ ((row & 7) << 3))];
  return __builtin_bit_cast(bf8_t, u);
}

// Write a thread's two 16B chunks (rows r0 and r0+32, k-chunk k8) swizzled.
__device__ __forceinline__ void st_tile_pair(unsigned short* lds, int r0, int k8, uint4 a0, uint4 a1) {
  int sw = ((k8 ^ (r0 & 7)) << 3);
  *(uint4*)&lds[(r0 << 6) + sw] = a0;
  *(uint4*)&lds[((r0 + 32) << 6) + sw] = a1;     // (r0+32)&7 == r0&7
}

__device__ __forceinline__ void mma_step(const unsigned short* As, const unsigned short* Ws,
                                         int w, int lane, f32x4 acc[4]) {
#pragma unroll
  for (int kk = 0; kk < 2; ++kk) {
    bf8_t a = ld_frag64(As, w << 4, kk, lane);
#pragma unroll
    for (int n = 0; n < 4; ++n)
      acc[n] = mfma16(a, ld_frag64(Ws, n << 4, kk, lane), acc[n]);
  }
}

// ---------------------------------------------------------------------------
// prep: convert q,k,v (3 x PH f32) and wq,wk,wv,wo (4 x WN f32) to bf16 into
// one contiguous dst region, in that order.  Chunk = 8 elems.
// ---------------------------------------------------------------------------
__global__ __launch_bounds__(256)
void prep(const float* __restrict__ q, const float* __restrict__ k, const float* __restrict__ v,
          const float* __restrict__ wq, const float* __restrict__ wk,
          const float* __restrict__ wv, const float* __restrict__ wo,
          unsigned short* __restrict__ dst) {
  const int QKV_C = PH / 8;           // 393216
  const int W_C   = WN / 8;           // 73728
  const int TOTAL = 3 * QKV_C + 4 * W_C;
  for (int c = blockIdx.x * 256 + threadIdx.x; c < TOTAL; c += gridDim.x * 256) {
    const float* s;
    int off;
    if (c < 3 * QKV_C) {
      int seg = c / QKV_C; off = c - seg * QKV_C;
      s = seg == 0 ? q : seg == 1 ? k : v;
    } else {
      int c2 = c - 3 * QKV_C;
      int seg = c2 / W_C; off = c2 - seg * W_C;
      s = seg == 0 ? wq : seg == 1 ? wk : seg == 2 ? wv : wo;
    }
    const float* p = s + (size_t)off * 8;
    float4 a = *(const float4*)p;
    float4 b = *(const float4*)(p + 4);
    uint4 o;
    o.x = pk2(a.x, a.y); o.y = pk2(a.z, a.w);
    o.z = pk2(b.x, b.y); o.w = pk2(b.z, b.w);
    *(uint4*)&dst[(size_t)c * 8] = o;
  }
}

// ---------------------------------------------------------------------------
// Fused QKV projection (bf16 in, bf16 out).  Grid 2304, 1D, XCD-chunked.
// z=0: Q -> [B,H,S,dk] * 0.125 ; z=1: K -> [B,H,S,dk] ; z=2: V -> [B,H,dk,S].
// ---------------------------------------------------------------------------
__global__ __launch_bounds__(256)
void qkv_proj(const unsigned short* __restrict__ Qc, const unsigned short* __restrict__ Kc,
              const unsigned short* __restrict__ Vc,
              const unsigned short* __restrict__ Wq, const unsigned short* __restrict__ Wk,
              const unsigned short* __restrict__ Wv,
              const float* __restrict__ bq, const float* __restrict__ bk,
              const float* __restrict__ bv,
              unsigned short* __restrict__ Qh, unsigned short* __restrict__ Kh,
              unsigned short* __restrict__ VT) {
  __shared__ __align__(16) unsigned short As[4096];
  __shared__ __align__(16) unsigned short Ws[4096];
  const int tid = threadIdx.x, lane = tid & 63, w = tid >> 6;
  const int g = lane >> 4, qc = lane & 15;
  const int p = blockIdx.x;
  const int l = (p & 7) * 288 + (p >> 3);
  const int z = l / 768, rr = l % 768;
  const int m0 = (rr / 12) << 6, n0 = (rr % 12) << 6;

  const unsigned short* A = z == 0 ? Qc : z == 1 ? Kc : Vc;
  const unsigned short* W = z == 0 ? Wq : z == 1 ? Wk : Wv;
  const float* bias = z == 0 ? bq : z == 1 ? bk : bv;
  const float oscale = z == 0 ? 0.125f : 1.0f;

  const int r0 = tid >> 3, k8 = tid & 7;
  const unsigned short* Ab0 = A + (size_t)(m0 + r0) * D_MODEL + (k8 << 3);
  const unsigned short* Ab1 = Ab0 + 32 * D_MODEL;
  const unsigned short* Wb0 = W + (size_t)(n0 + r0) * D_MODEL + (k8 << 3);
  const unsigned short* Wb1 = Wb0 + 32 * D_MODEL;

  uint4 ra0 = *(const uint4*)Ab0, ra1 = *(const uint4*)Ab1;
  uint4 rw0 = *(const uint4*)Wb0, rw1 = *(const uint4*)Wb1;

  f32x4 acc[4] = {};
  for (int kt = 0; kt < 12; ++kt) {
    __syncthreads();
    st_tile_pair(As, r0, k8, ra0, ra1);
    st_tile_pair(Ws, r0, k8, rw0, rw1);
    __syncthreads();
    if (kt < 11) {
      int off = (kt + 1) << 6;
      ra0 = *(const uint4*)(Ab0 + off); ra1 = *(const uint4*)(Ab1 + off);
      rw0 = *(const uint4*)(Wb0 + off); rw1 = *(const uint4*)(Wb1 + off);
    }
    mma_step(As, Ws, w, lane, acc);
  }

  const int wrow = (w << 4) + (g << 2);
  const int b = m0 >> 11;
  const int h = n0 >> 6;
  if (z < 2) {
    unsigned short* dst = (z == 0 ? Qh : Kh) + ((size_t)(b * N_HEADS + h)) * SS * DK;
#pragma unroll
    for (int n = 0; n < 4; ++n) {
      int col = (n << 4) + qc;
      float bb = bias[n0 + col];
#pragma unroll
      for (int r = 0; r < 4; ++r) {
        int s = (m0 + wrow + r) & (SS - 1);
        dst[(size_t)s * DK + col] = f2b((acc[n][r] + bb) * oscale);
      }
    }
  } else {
    unsigned short* dst = VT + ((size_t)(b * N_HEADS + h)) * DK * SS;
#pragma unroll
    for (int n = 0; n < 4; ++n) {
      int col = (n << 4) + qc;        // d index
      float bb = bias[n0 + col];
      int s = (m0 + wrow) & (SS - 1);
      ushort4 pk;
      pk.x = f2b(acc[n][0] + bb); pk.y = f2b(acc[n][1] + bb);
      pk.z = f2b(acc[n][2] + bb); pk.w = f2b(acc[n][3] + bb);
      *(ushort4*)&dst[(size_t)col * SS + s] = pk;
    }
  }
}

// ---------------------------------------------------------------------------
// MFMA causal attention, prefetched staging, Q in registers.
// Pass 1: K double-buffered across Ks/Vts (Vts unused in pass 1) ->
//         ONE barrier per k-tile.  Pass 2: identical to round-3 structure.
// Grid 768 1D XCD-chunked: 24 bh x 32 paired q-tiles of 64 rows.
// ---------------------------------------------------------------------------
__global__ __launch_bounds__(256)
void attn2(const unsigned short* __restrict__ Qh, const unsigned short* __restrict__ Kh,
           const unsigned short* __restrict__ VT,
           float* __restrict__ attn, unsigned short* __restrict__ ctx) {
  __shared__ __align__(16) unsigned short Ks[4096];
  __shared__ __align__(16) unsigned short Vts[4096];
  __shared__ __align__(16) unsigned short Pw[4][1024];

  const int tid = threadIdx.x, lane = tid & 63, w = tid >> 6;
  const int g = lane >> 4, qc = lane & 15;
  const int p = blockIdx.x;
  const int l = (p & 7) * 96 + (p >> 3);
  const int bh = l >> 5;
  const int x = l & 31;
  const int qt = (x & 1) ? (31 - (x >> 1)) : (x >> 1);
  const int q0 = qt << 6;
  const int b = bh / N_HEADS, h = bh - b * N_HEADS;

  const unsigned short* Qb = Qh + (size_t)bh * SS * DK;
  const unsigned short* Kb = Kh + (size_t)bh * SS * DK;
  const unsigned short* Vb = VT + (size_t)bh * DK * SS;
  float* attn_b = attn + (size_t)bh * SS * SS;

  // Q fragments straight from global
  bf8_t qf0, qf1;
  {
    const unsigned short* qp = &Qb[(size_t)(q0 + (w << 4) + (lane & 15)) * DK + (g << 3)];
    qf0 = __builtin_bit_cast(bf8_t, *(const uint4*)qp);
    qf1 = __builtin_bit_cast(bf8_t, *(const uint4*)(qp + 32));
  }

  const int r0 = tid >> 3, k8 = tid & 7;
  auto ldK = [&](int t, uint4& a0, uint4& a1) {
    const unsigned short* bse = Kb + ((size_t)t << 12);
    a0 = *(const uint4*)&bse[(r0 << 6) + (k8 << 3)];
    a1 = *(const uint4*)&bse[((r0 + 32) << 6) + (k8 << 3)];
  };
  auto ldV = [&](int t, uint4& a0, uint4& a1) {
    const unsigned short* bse = Vb + (t << 6);
    a0 = *(const uint4*)&bse[(size_t)r0 * SS + (k8 << 3)];
    a1 = *(const uint4*)&bse[(size_t)(r0 + 32) * SS + (k8 << 3)];
  };

  const int wrow = (w << 4) + (g << 2);
  float l_acc[4] = {0.f, 0.f, 0.f, 0.f};

  // ---------------- pass 1: row sums (dbuf K across Ks/Vts, 1 barrier/tile) --
  {
    uint4 ka0, ka1;
    ldK(0, ka0, ka1);
    st_tile_pair(Ks, r0, k8, ka0, ka1);     // stage tile 0 into Ks
    for (int t = 0; t <= qt; ++t) {
      unsigned short* KB = (t & 1) ? Vts : Ks;
      __syncthreads();                       // staged writes of KB visible
      if (t < qt) ldK(t + 1, ka0, ka1);      // prefetch next tile (global)
      f32x4 sc[4] = {};
#pragma unroll
      for (int kk = 0; kk < 2; ++kk) {
        bf8_t a = kk ? qf1 : qf0;
#pragma unroll
        for (int n = 0; n < 4; ++n)
          sc[n] = mfma16(a, ld_frag64(KB, n << 4, kk, lane), sc[n]);
      }
      const bool diag = (t == qt);
      float part[4] = {0.f, 0.f, 0.f, 0.f};
#pragma unroll
      for (int n = 0; n < 4; ++n) {
        int col = (n << 4) + qc;
#pragma unroll
        for (int r = 0; r < 4; ++r) {
          bool ok = !diag || (col <= wrow + r);
          part[r] += ok ? __expf(sc[n][r]) : 0.f;
        }
      }
#pragma unroll
      for (int r = 0; r < 4; ++r) {
        float s = part[r];
        s += __shfl_xor(s, 1);
        s += __shfl_xor(s, 2);
        s += __shfl_xor(s, 4);
        s += __shfl_xor(s, 8);
        l_acc[r] += s;
      }
      if (t < qt) {
        // stage next tile into the OTHER buffer; its previous readers finished
        // before the barrier at the top of this iteration.
        unsigned short* KN = (t & 1) ? Ks : Vts;
        st_tile_pair(KN, r0, k8, ka0, ka1);
      }
    }
  }

  float Linv[4];
#pragma unroll
  for (int r = 0; r < 4; ++r) Linv[r] = 1.0f / l_acc[r];

  // ---------------- pass 2: attn write + PV ----------------
  f32x4 ct[4] = {};
  unsigned short* myP = Pw[w];
  {
    uint4 ka0, ka1, va0, va1;
    ldK(0, ka0, ka1);
    ldV(0, va0, va1);
    for (int t = 0; t <= qt; ++t) {
      __syncthreads();
      st_tile_pair(Ks, r0, k8, ka0, ka1);
      st_tile_pair(Vts, r0, k8, va0, va1);
      __syncthreads();
      if (t < qt) { ldK(t + 1, ka0, ka1); ldV(t + 1, va0, va1); }
      f32x4 sc[4] = {};
#pragma unroll
      for (int kk = 0; kk < 2; ++kk) {
        bf8_t a = kk ? qf1 : qf0;
#pragma unroll
        for (int n = 0; n < 4; ++n)
          sc[n] = mfma16(a, ld_frag64(Ks, n << 4, kk, lane), sc[n]);
      }
      const bool diag = (t == qt);
      const int k0 = t << 6;
#pragma unroll
      for (int n = 0; n < 4; ++n) {
        int col = (n << 4) + qc;
#pragma unroll
        for (int r = 0; r < 4; ++r) {
          bool ok = !diag || (col <= wrow + r);
          float pv = ok ? __expf(sc[n][r]) * Linv[r] : 0.f;
          attn_b[(size_t)(q0 + wrow + r) * SS + k0 + col] = pv;
          int prow = (g << 2) + r;
          myP[(prow << 6) + (col ^ ((prow & 7) << 3))] = f2b(pv);
        }
      }
      asm volatile("s_waitcnt lgkmcnt(0)" ::: "memory");
      __builtin_amdgcn_sched_barrier(0);
#pragma unroll
      for (int kk = 0; kk < 2; ++kk) {
        bf8_t pf = ld_frag64(myP, 0, kk, lane);
#pragma unroll
        for (int n = 0; n < 4; ++n)
          ct[n] = mfma16(pf, ld_frag64(Vts, n << 4, kk, lane), ct[n]);
      }
    }
  }

  // zero-fill masked upper-triangular tiles (coalesced float4)
  {
    const int zr = tid >> 4;
    const int zc = (tid & 15) << 2;
    const float4 z4 = {0.f, 0.f, 0.f, 0.f};
    for (int c0 = q0 + 64; c0 < SS; c0 += 64) {
#pragma unroll
      for (int i = 0; i < 4; ++i)
        *(float4*)&attn_b[(size_t)(q0 + zr + (i << 4)) * SS + c0 + zc] = z4;
    }
  }

  // ctx (bf16) as [B, S, H*dk]
#pragma unroll
  for (int n = 0; n < 4; ++n) {
#pragma unroll
    for (int r = 0; r < 4; ++r) {
      int m = q0 + wrow + r;
      int col = (n << 4) + qc;
      ctx[((size_t)(b * SS + m)) * D_MODEL + h * DK + col] = f2b(ct[n][r]);
    }
  }
}

// ---------------------------------------------------------------------------
// Output projection: bf16 A [4096][768] @ bf16 Wo^T + bo -> f32.  64x64 tile.
// ---------------------------------------------------------------------------
__global__ __launch_bounds__(256)
void out_proj(const unsigned short* __restrict__ A, const unsigned short* __restrict__ W,
              const float* __restrict__ bias, float* __restrict__ out) {
  __shared__ __align__(16) unsigned short As[4096];
  __shared__ __align__(16) unsigned short Ws[4096];
  const int tid = threadIdx.x, lane = tid & 63, w = tid >> 6;
  const int g = lane >> 4, qc = lane & 15;
  const int p = blockIdx.x;
  const int l = (p & 7) * 96 + (p >> 3);
  const int m0 = (l / 12) << 6, n0 = (l % 12) << 6;

  const int r0 = tid >> 3, k8 = tid & 7;
  const unsigned short* Ab0 = A + (size_t)(m0 + r0) * D_MODEL + (k8 << 3);
  const unsigned short* Ab1 = Ab0 + 32 * D_MODEL;
  const unsigned short* Wb0 = W + (size_t)(n0 + r0) * D_MODEL + (k8 << 3);
  const unsigned short* Wb1 = Wb0 + 32 * D_MODEL;

  uint4 ra0 = *(const uint4*)Ab0, ra1 = *(const uint4*)Ab1;
  uint4 rw0 = *(const uint4*)Wb0, rw1 = *(const uint4*)Wb1;

  f32x4 acc[4] = {};
  for (int kt = 0; kt < 12; ++kt) {
    __syncthreads();
    st_tile_pair(As, r0, k8, ra0, ra1);
    st_tile_pair(Ws, r0, k8, rw0, rw1);
    __syncthreads();
    if (kt < 11) {
      int off = (kt + 1) << 6;
      ra0 = *(const uint4*)(Ab0 + off); ra1 = *(const uint4*)(Ab1 + off);
      rw0 = *(const uint4*)(Wb0 + off); rw1 = *(const uint4*)(Wb1 + off);
    }
    mma_step(As, Ws, w, lane, acc);
  }

  const int wrow = (w << 4) + (g << 2);
#pragma unroll
  for (int n = 0; n < 4; ++n) {
    int col = n0 + (n << 4) + qc;
    float bb = bias[col];
#pragma unroll
    for (int r = 0; r < 4; ++r)
      out[(size_t)(m0 + wrow + r) * D_MODEL + col] = acc[n][r] + bb;
  }
}

// ---------------------------------------------------------------------------
extern "C" void kernel_launch(void* const* d_in, const int* in_sizes, int n_in,
                              void* d_out, int out_size, void* d_ws, size_t ws_size,
                              hipStream_t stream) {
  const float* q  = (const float*)d_in[0];
  const float* k  = (const float*)d_in[1];
  const float* v  = (const float*)d_in[2];
  // d_in[3] = mask (int32 tril; causal structure exploited directly)
  const float* wq = (const float*)d_in[4];
  const float* bq = (const float*)d_in[5];
  const float* wk = (const float*)d_in[6];
  const float* bk = (const float*)d_in[7];
  const float* wv = (const float*)d_in[8];
  const float* bv = (const float*)d_in[9];
  const float* wo = (const float*)d_in[10];
  const float* bo = (const float*)d_in[11];

  float* out  = (float*)d_out;                    // [B*S, 768]
  float* attn = out + (size_t)BB * SS * D_MODEL;  // [B*H, S, S]

  unsigned short* wsu = (unsigned short*)d_ws;
  unsigned short* Qc  = wsu;
  unsigned short* Kc  = Qc + PH;
  unsigned short* Vc  = Kc + PH;
  unsigned short* Wqb = Vc + PH;
  unsigned short* Wkb = Wqb + WN;
  unsigned short* Wvb = Wkb + WN;
  unsigned short* Wob = Wvb + WN;
  unsigned short* Qhd = Wob + WN;                 // [B,H,S,dk]
  unsigned short* Khd = Qhd + PH;
  unsigned short* VTw = Khd + PH;                 // [B,H,dk,S]
  unsigned short* Cw  = VTw + PH;                 // [B,S,768]

  dim3 blk(256);
  prep<<<2048, blk, 0, stream>>>(q, k, v, wq, wk, wv, wo, wsu);
  qkv_proj<<<2304, blk, 0, stream>>>(Qc, Kc, Vc, Wqb, Wkb, Wvb, bq, bk, bv, Qhd, Khd, VTw);
  attn2<<<768, blk, 0, stream>>>(Qhd, Khd, VTw, attn, Cw);
  out_proj<<<768, blk, 0, stream>>>(Cw, Wob, bo, out);
}

// Round 7
// 171.953 us; speedup vs baseline: 1.1253x; 1.0665x over previous
//
#include <hip/hip_runtime.h>

#define D_MODEL 768
#define N_HEADS 12
#define DK      64
#define BB      2
#define SS      2048
#define PH      (BB*SS*D_MODEL)      // 3,145,728 elems
#define WN      (D_MODEL*D_MODEL)    // 589,824 elems

typedef short bf8_t   __attribute__((ext_vector_type(8)));   // 8 x bf16 bits
typedef float f32x4   __attribute__((ext_vector_type(4)));

// f32 -> bf16 bits, round-to-nearest-even (finite inputs)
__device__ __forceinline__ unsigned short f2b(float f) {
  unsigned u = __builtin_bit_cast(unsigned, f);
  unsigned r = (u + 0x7FFFu + ((u >> 16) & 1u)) >> 16;
  return (unsigned short)r;
}
__device__ __forceinline__ unsigned pk2(float a, float b) {
  return (unsigned)f2b(a) | ((unsigned)f2b(b) << 16);
}
__device__ __forceinline__ f32x4 mfma16(bf8_t a, bf8_t b, f32x4 c) {
  return __builtin_amdgcn_mfma_f32_16x16x32_bf16(a, b, c, 0, 0, 0);
}

// Load one 16x32 fragment from a swizzled 64-wide bf16 LDS tile.
// lane: row = rbase + (lane&15), k = kk*32 + (lane>>4)*8 + j (j=0..7)
__device__ __forceinline__ bf8_t ld_frag64(const unsigned short* t, int rbase, int kk, int lane) {
  int row = rbase + (lane & 15);
  int k = (kk << 5) + ((lane >> 4) << 3);
  uint4 u = *(const uint4*)&t[(row << 6) + (k ^ ((row & 7) << 3))];
  return __builtin_bit_cast(bf8_t, u);
}

// Write a thread's two 16B chunks (rows r0 and r0+32, k-chunk k8) swizzled.
__device__ __forceinline__ void st_tile_pair(unsigned short* lds, int r0, int k8, uint4 a0, uint4 a1) {
  int sw = ((k8 ^ (r0 & 7)) << 3);
  *(uint4*)&lds[(r0 << 6) + sw] = a0;
  *(uint4*)&lds[((r0 + 32) << 6) + sw] = a1;     // (r0+32)&7 == r0&7
}

__device__ __forceinline__ void mma_step(const unsigned short* As, const unsigned short* Ws,
                                         int w, int lane, f32x4 acc[4]) {
#pragma unroll
  for (int kk = 0; kk < 2; ++kk) {
    bf8_t a = ld_frag64(As, w << 4, kk, lane);
#pragma unroll
    for (int n = 0; n < 4; ++n)
      acc[n] = mfma16(a, ld_frag64(Ws, n << 4, kk, lane), acc[n]);
  }
}

// ---------------------------------------------------------------------------
// prep: convert q,k,v (3 x PH f32) and wq,wk,wv,wo (4 x WN f32) to bf16 into
// one contiguous dst region, in that order.  Chunk = 8 elems.
// ---------------------------------------------------------------------------
__global__ __launch_bounds__(256)
void prep(const float* __restrict__ q, const float* __restrict__ k, const float* __restrict__ v,
          const float* __restrict__ wq, const float* __restrict__ wk,
          const float* __restrict__ wv, const float* __restrict__ wo,
          unsigned short* __restrict__ dst) {
  const int QKV_C = PH / 8;           // 393216
  const int W_C   = WN / 8;           // 73728
  const int TOTAL = 3 * QKV_C + 4 * W_C;
  for (int c = blockIdx.x * 256 + threadIdx.x; c < TOTAL; c += gridDim.x * 256) {
    const float* s;
    int off;
    if (c < 3 * QKV_C) {
      int seg = c / QKV_C; off = c - seg * QKV_C;
      s = seg == 0 ? q : seg == 1 ? k : v;
    } else {
      int c2 = c - 3 * QKV_C;
      int seg = c2 / W_C; off = c2 - seg * W_C;
      s = seg == 0 ? wq : seg == 1 ? wk : seg == 2 ? wv : wo;
    }
    const float* p = s + (size_t)off * 8;
    float4 a = *(const float4*)p;
    float4 b = *(const float4*)(p + 4);
    uint4 o;
    o.x = pk2(a.x, a.y); o.y = pk2(a.z, a.w);
    o.z = pk2(b.x, b.y); o.w = pk2(b.z, b.w);
    *(uint4*)&dst[(size_t)c * 8] = o;
  }
}

// ---------------------------------------------------------------------------
// Fused QKV projection (bf16 in, bf16 out).  Grid 2304, 1D, XCD-chunked.
// z=0: Q -> [B,H,S,dk] * 0.125 ; z=1: K -> [B,H,S,dk] ; z=2: V -> [B,H,dk,S].
// ---------------------------------------------------------------------------
__global__ __launch_bounds__(256)
void qkv_proj(const unsigned short* __restrict__ Qc, const unsigned short* __restrict__ Kc,
              const unsigned short* __restrict__ Vc,
              const unsigned short* __restrict__ Wq, const unsigned short* __restrict__ Wk,
              const unsigned short* __restrict__ Wv,
              const float* __restrict__ bq, const float* __restrict__ bk,
              const float* __restrict__ bv,
              unsigned short* __restrict__ Qh, unsigned short* __restrict__ Kh,
              unsigned short* __restrict__ VT) {
  __shared__ __align__(16) unsigned short As[4096];
  __shared__ __align__(16) unsigned short Ws[4096];
  const int tid = threadIdx.x, lane = tid & 63, w = tid >> 6;
  const int g = lane >> 4, qc = lane & 15;
  const int p = blockIdx.x;
  const int l = (p & 7) * 288 + (p >> 3);
  const int z = l / 768, rr = l % 768;
  const int m0 = (rr / 12) << 6, n0 = (rr % 12) << 6;

  const unsigned short* A = z == 0 ? Qc : z == 1 ? Kc : Vc;
  const unsigned short* W = z == 0 ? Wq : z == 1 ? Wk : Wv;
  const float* bias = z == 0 ? bq : z == 1 ? bk : bv;
  const float oscale = z == 0 ? 0.125f : 1.0f;

  const int r0 = tid >> 3, k8 = tid & 7;
  const unsigned short* Ab0 = A + (size_t)(m0 + r0) * D_MODEL + (k8 << 3);
  const unsigned short* Ab1 = Ab0 + 32 * D_MODEL;
  const unsigned short* Wb0 = W + (size_t)(n0 + r0) * D_MODEL + (k8 << 3);
  const unsigned short* Wb1 = Wb0 + 32 * D_MODEL;

  uint4 ra0 = *(const uint4*)Ab0, ra1 = *(const uint4*)Ab1;
  uint4 rw0 = *(const uint4*)Wb0, rw1 = *(const uint4*)Wb1;

  f32x4 acc[4] = {};
  for (int kt = 0; kt < 12; ++kt) {
    __syncthreads();
    st_tile_pair(As, r0, k8, ra0, ra1);
    st_tile_pair(Ws, r0, k8, rw0, rw1);
    __syncthreads();
    if (kt < 11) {
      int off = (kt + 1) << 6;
      ra0 = *(const uint4*)(Ab0 + off); ra1 = *(const uint4*)(Ab1 + off);
      rw0 = *(const uint4*)(Wb0 + off); rw1 = *(const uint4*)(Wb1 + off);
    }
    mma_step(As, Ws, w, lane, acc);
  }

  const int wrow = (w << 4) + (g << 2);
  const int b = m0 >> 11;
  const int h = n0 >> 6;
  if (z < 2) {
    unsigned short* dst = (z == 0 ? Qh : Kh) + ((size_t)(b * N_HEADS + h)) * SS * DK;
#pragma unroll
    for (int n = 0; n < 4; ++n) {
      int col = (n << 4) + qc;
      float bb = bias[n0 + col];
#pragma unroll
      for (int r = 0; r < 4; ++r) {
        int s = (m0 + wrow + r) & (SS - 1);
        dst[(size_t)s * DK + col] = f2b((acc[n][r] + bb) * oscale);
      }
    }
  } else {
    unsigned short* dst = VT + ((size_t)(b * N_HEADS + h)) * DK * SS;
#pragma unroll
    for (int n = 0; n < 4; ++n) {
      int col = (n << 4) + qc;        // d index
      float bb = bias[n0 + col];
      int s = (m0 + wrow) & (SS - 1);
      ushort4 pk;
      pk.x = f2b(acc[n][0] + bb); pk.y = f2b(acc[n][1] + bb);
      pk.z = f2b(acc[n][2] + bb); pk.w = f2b(acc[n][3] + bb);
      *(ushort4*)&dst[(size_t)col * SS + s] = pk;
    }
  }
}

// ---------------------------------------------------------------------------
// MFMA causal attention.  Round-3 staging/barrier structure, but scores
// computed TRANSPOSED: S^T = mfma(K_frag, Q_frag) so each lane owns ONE
// q-row (q = q0 + w*16 + qc) and 16 k values (k = k0 + n*16 + g*4 + r).
// Epilogue: 4 float4 attn stores + 4 ds_write_b64 P writes per lane
// (was 16 scalar dword stores + 16 ds_write_b16); row-sum reduce deferred
// to 2 shuffles per pass.
// Grid 768 1D XCD-chunked: 24 bh x 32 paired q-tiles of 64 rows.
// ---------------------------------------------------------------------------
__global__ __launch_bounds__(256)
void attn4(const unsigned short* __restrict__ Qh, const unsigned short* __restrict__ Kh,
           const unsigned short* __restrict__ VT,
           float* __restrict__ attn, unsigned short* __restrict__ ctx) {
  __shared__ __align__(16) unsigned short Ks[4096];
  __shared__ __align__(16) unsigned short Vts[4096];
  __shared__ __align__(16) unsigned short Pw[4][1024];

  const int tid = threadIdx.x, lane = tid & 63, w = tid >> 6;
  const int g = lane >> 4, qc = lane & 15;
  const int p = blockIdx.x;
  const int l = (p & 7) * 96 + (p >> 3);
  const int bh = l >> 5;
  const int x = l & 31;
  const int qt = (x & 1) ? (31 - (x >> 1)) : (x >> 1);
  const int q0 = qt << 6;
  const int b = bh / N_HEADS, h = bh - b * N_HEADS;

  const unsigned short* Qb = Qh + (size_t)bh * SS * DK;
  const unsigned short* Kb = Kh + (size_t)bh * SS * DK;
  const unsigned short* Vb = VT + (size_t)bh * DK * SS;
  float* attn_b = attn + (size_t)bh * SS * SS;

  // Q fragments straight from global (B-operand for the S^T mfma)
  bf8_t qf0, qf1;
  {
    const unsigned short* qp = &Qb[(size_t)(q0 + (w << 4) + qc) * DK + (g << 3)];
    qf0 = __builtin_bit_cast(bf8_t, *(const uint4*)qp);
    qf1 = __builtin_bit_cast(bf8_t, *(const uint4*)(qp + 32));
  }

  const int r0 = tid >> 3, k8 = tid & 7;
  auto ldK = [&](int t, uint4& a0, uint4& a1) {
    const unsigned short* bse = Kb + ((size_t)t << 12);
    a0 = *(const uint4*)&bse[(r0 << 6) + (k8 << 3)];
    a1 = *(const uint4*)&bse[((r0 + 32) << 6) + (k8 << 3)];
  };
  auto ldV = [&](int t, uint4& a0, uint4& a1) {
    const unsigned short* bse = Vb + (t << 6);
    a0 = *(const uint4*)&bse[(size_t)r0 * SS + (k8 << 3)];
    a1 = *(const uint4*)&bse[(size_t)(r0 + 32) * SS + (k8 << 3)];
  };

  const int qglob = q0 + (w << 4) + qc;   // this lane's q row
  float psum = 0.f;

  // ---------------- pass 1: row sums ----------------
  {
    uint4 ka0, ka1;
    ldK(0, ka0, ka1);
    for (int t = 0; t <= qt; ++t) {
      __syncthreads();
      st_tile_pair(Ks, r0, k8, ka0, ka1);
      __syncthreads();
      if (t < qt) ldK(t + 1, ka0, ka1);
      f32x4 sc[4] = {};
#pragma unroll
      for (int kk = 0; kk < 2; ++kk) {
        bf8_t qf = kk ? qf1 : qf0;
#pragma unroll
        for (int n = 0; n < 4; ++n)
          sc[n] = mfma16(ld_frag64(Ks, n << 4, kk, lane), qf, sc[n]);
      }
      const bool diag = (t == qt);
      const int kbase = (t << 6) + (g << 2);
#pragma unroll
      for (int n = 0; n < 4; ++n) {
#pragma unroll
        for (int r = 0; r < 4; ++r) {
          int k = kbase + (n << 4) + r;
          bool ok = !diag || (k <= qglob);
          psum += ok ? __expf(sc[n][r]) : 0.f;
        }
      }
    }
  }
  // deferred cross-lane reduce: lanes {qc, qc+16, qc+32, qc+48} share one q
  psum += __shfl_xor(psum, 16);
  psum += __shfl_xor(psum, 32);
  const float Linv = 1.0f / psum;

  // ---------------- pass 2: attn write + PV ----------------
  f32x4 ct[4] = {};
  unsigned short* myP = Pw[w];
  {
    uint4 ka0, ka1, va0, va1;
    ldK(0, ka0, ka1);
    ldV(0, va0, va1);
    for (int t = 0; t <= qt; ++t) {
      __syncthreads();
      st_tile_pair(Ks, r0, k8, ka0, ka1);
      st_tile_pair(Vts, r0, k8, va0, va1);
      __syncthreads();
      if (t < qt) { ldK(t + 1, ka0, ka1); ldV(t + 1, va0, va1); }
      f32x4 sc[4] = {};
#pragma unroll
      for (int kk = 0; kk < 2; ++kk) {
        bf8_t qf = kk ? qf1 : qf0;
#pragma unroll
        for (int n = 0; n < 4; ++n)
          sc[n] = mfma16(ld_frag64(Ks, n << 4, kk, lane), qf, sc[n]);
      }
      const bool diag = (t == qt);
      const int k0 = t << 6;
#pragma unroll
      for (int n = 0; n < 4; ++n) {
        int klocal = (n << 4) + (g << 2);          // k within tile, 4-aligned
        int kb = k0 + klocal;
        float pr[4];
#pragma unroll
        for (int r = 0; r < 4; ++r) {
          bool ok = !diag || (kb + r <= qglob);
          pr[r] = ok ? __expf(sc[n][r]) * Linv : 0.f;
        }
        float4 pv;
        pv.x = pr[0]; pv.y = pr[1]; pv.z = pr[2]; pv.w = pr[3];
        *(float4*)&attn_b[(size_t)qglob * SS + kb] = pv;
        // P -> wave-private LDS tile [qlocal=16][klocal=64], swizzled
        uint2 pk;
        pk.x = pk2(pr[0], pr[1]);
        pk.y = pk2(pr[2], pr[3]);
        *(uint2*)&myP[(qc << 6) + (klocal ^ ((qc & 7) << 3))] = pk;
      }
      asm volatile("s_waitcnt lgkmcnt(0)" ::: "memory");
      __builtin_amdgcn_sched_barrier(0);
#pragma unroll
      for (int kk = 0; kk < 2; ++kk) {
        bf8_t pf = ld_frag64(myP, 0, kk, lane);
#pragma unroll
        for (int n = 0; n < 4; ++n)
          ct[n] = mfma16(pf, ld_frag64(Vts, n << 4, kk, lane), ct[n]);
      }
    }
  }

  // zero-fill masked upper-triangular tiles (coalesced float4)
  {
    const int zr = tid >> 4;
    const int zc = (tid & 15) << 2;
    const float4 z4 = {0.f, 0.f, 0.f, 0.f};
    for (int c0 = q0 + 64; c0 < SS; c0 += 64) {
#pragma unroll
      for (int i = 0; i < 4; ++i)
        *(float4*)&attn_b[(size_t)(q0 + zr + (i << 4)) * SS + c0 + zc] = z4;
    }
  }

  // ctx (bf16) as [B, S, H*dk];  PV C-layout: row=qlocal=(g<<2)+r, col=d=(n<<4)+qc
  const int wrow = (w << 4) + (g << 2);
#pragma unroll
  for (int n = 0; n < 4; ++n) {
#pragma unroll
    for (int r = 0; r < 4; ++r) {
      int m = q0 + wrow + r;
      int col = (n << 4) + qc;
      ctx[((size_t)(b * SS + m)) * D_MODEL + h * DK + col] = f2b(ct[n][r]);
    }
  }
}

// ---------------------------------------------------------------------------
// Output projection: bf16 A [4096][768] @ bf16 Wo^T + bo -> f32.  64x64 tile.
// ---------------------------------------------------------------------------
__global__ __launch_bounds__(256)
void out_proj(const unsigned short* __restrict__ A, const unsigned short* __restrict__ W,
              const float* __restrict__ bias, float* __restrict__ out) {
  __shared__ __align__(16) unsigned short As[4096];
  __shared__ __align__(16) unsigned short Ws[4096];
  const int tid = threadIdx.x, lane = tid & 63, w = tid >> 6;
  const int g = lane >> 4, qc = lane & 15;
  const int p = blockIdx.x;
  const int l = (p & 7) * 96 + (p >> 3);
  const int m0 = (l / 12) << 6, n0 = (l % 12) << 6;

  const int r0 = tid >> 3, k8 = tid & 7;
  const unsigned short* Ab0 = A + (size_t)(m0 + r0) * D_MODEL + (k8 << 3);
  const unsigned short* Ab1 = Ab0 + 32 * D_MODEL;
  const unsigned short* Wb0 = W + (size_t)(n0 + r0) * D_MODEL + (k8 << 3);
  const unsigned short* Wb1 = Wb0 + 32 * D_MODEL;

  uint4 ra0 = *(const uint4*)Ab0, ra1 = *(const uint4*)Ab1;
  uint4 rw0 = *(const uint4*)Wb0, rw1 = *(const uint4*)Wb1;

  f32x4 acc[4] = {};
  for (int kt = 0; kt < 12; ++kt) {
    __syncthreads();
    st_tile_pair(As, r0, k8, ra0, ra1);
    st_tile_pair(Ws, r0, k8, rw0, rw1);
    __syncthreads();
    if (kt < 11) {
      int off = (kt + 1) << 6;
      ra0 = *(const uint4*)(Ab0 + off); ra1 = *(const uint4*)(Ab1 + off);
      rw0 = *(const uint4*)(Wb0 + off); rw1 = *(const uint4*)(Wb1 + off);
    }
    mma_step(As, Ws, w, lane, acc);
  }

  const int wrow = (w << 4) + (g << 2);
#pragma unroll
  for (int n = 0; n < 4; ++n) {
    int col = n0 + (n << 4) + qc;
    float bb = bias[col];
#pragma unroll
    for (int r = 0; r < 4; ++r)
      out[(size_t)(m0 + wrow + r) * D_MODEL + col] = acc[n][r] + bb;
  }
}

// ---------------------------------------------------------------------------
extern "C" void kernel_launch(void* const* d_in, const int* in_sizes, int n_in,
                              void* d_out, int out_size, void* d_ws, size_t ws_size,
                              hipStream_t stream) {
  const float* q  = (const float*)d_in[0];
  const float* k  = (const float*)d_in[1];
  const float* v  = (const float*)d_in[2];
  // d_in[3] = mask (int32 tril; causal structure exploited directly)
  const float* wq = (const float*)d_in[4];
  const float* bq = (const float*)d_in[5];
  const float* wk = (const float*)d_in[6];
  const float* bk = (const float*)d_in[7];
  const float* wv = (const float*)d_in[8];
  const float* bv = (const float*)d_in[9];
  const float* wo = (const float*)d_in[10];
  const float* bo = (const float*)d_in[11];

  float* out  = (float*)d_out;                    // [B*S, 768]
  float* attn = out + (size_t)BB * SS * D_MODEL;  // [B*H, S, S]

  unsigned short* wsu = (unsigned short*)d_ws;
  unsigned short* Qc  = wsu;
  unsigned short* Kc  = Qc + PH;
  unsigned short* Vc  = Kc + PH;
  unsigned short* Wqb = Vc + PH;
  unsigned short* Wkb = Wqb + WN;
  unsigned short* Wvb = Wkb + WN;
  unsigned short* Wob = Wvb + WN;
  unsigned short* Qhd = Wob + WN;                 // [B,H,S,dk]
  unsigned short* Khd = Qhd + PH;
  unsigned short* VTw = Khd + PH;                 // [B,H,dk,S]
  unsigned short* Cw  = VTw + PH;                 // [B,S,768]

  dim3 blk(256);
  prep<<<2048, blk, 0, stream>>>(q, k, v, wq, wk, wv, wo, wsu);
  qkv_proj<<<2304, blk, 0, stream>>>(Qc, Kc, Vc, Wqb, Wkb, Wvb, bq, bk, bv, Qhd, Khd, VTw);
  attn4<<<768, blk, 0, stream>>>(Qhd, Khd, VTw, attn, Cw);
  out_proj<<<768, blk, 0, stream>>>(Cw, Wob, bo, out);
}